// Round 2
// baseline (125.862 us; speedup 1.0000x reference)
//
#include <hip/hip_runtime.h>

#define B_   128
#define L_   26
#define C1_  128
#define C2_  64
#define K1_  7
#define K2_  5
#define NPOS 25
#define FEAT (L_*C2_)   // 1664

// ---------------------------------------------------------------------------
// Kernel A: one-hot -> conv1(k7,relu) -> conv2(k5,relu) -> featT[u][b]
// u = l*64 + c2 ; featT stored transposed (b innermost) for coalesced reads.
// grid = 128 b * 4 c2-tiles ; block = 256
// ---------------------------------------------------------------------------
__global__ __launch_bounds__(256) void conv_kernel(
    const int*   __restrict__ x,
    const float* __restrict__ w1, const float* __restrict__ b1,
    const float* __restrict__ w2, const float* __restrict__ b2,
    float* __restrict__ featT)
{
    __shared__ float h1s[C1_][L_ + 4];   // index [c1][pos+2], pads are zero
    __shared__ int   xs[L_];

    const int bid = blockIdx.x;
    const int b   = bid >> 2;
    const int c2t = bid & 3;
    const int t   = threadIdx.x;

    if (t < L_)  xs[t] = x[b*L_ + t];
    if (t < C1_) { h1s[t][0] = 0.f; h1s[t][1] = 0.f;
                   h1s[t][L_+2] = 0.f; h1s[t][L_+3] = 0.f; }
    __syncthreads();

    // stage 1: h1[c1][l] = relu(b1 + sum_k w1[c1][x[l+k-3]][k])
    for (int idx = t; idx < C1_*L_; idx += 256) {
        const int c1 = idx / L_;
        const int l  = idx - c1*L_;
        float s = b1[c1];
        const float* w1r = w1 + c1*4*K1_;
        #pragma unroll
        for (int k = 0; k < K1_; ++k) {
            const int pos = l + k - 3;
            if (pos >= 0 && pos < L_) s += w1r[xs[pos]*K1_ + k];
        }
        h1s[c1][l+2] = fmaxf(s, 0.f);
    }
    __syncthreads();

    // stage 2: 16 c2 values per block, all 26 l
    for (int o = t; o < 16*L_; o += 256) {
        const int l   = o % L_;
        const int c2i = o / L_;
        const int c2  = c2t*16 + c2i;
        float acc = b2[c2];
        const float* w2r = w2 + c2*C1_*K2_;
        for (int c1 = 0; c1 < C1_; ++c1) {
            const float* wr = w2r + c1*K2_;
            const float* hr = &h1s[c1][l];   // slot l+k == pos l+k-2 shifted by +2
            acc += wr[0]*hr[0] + wr[1]*hr[1] + wr[2]*hr[2]
                 + wr[3]*hr[3] + wr[4]*hr[4];
        }
        featT[(l*C2_ + c2)*B_ + b] = fmaxf(acc, 0.f);
    }
}

// ---------------------------------------------------------------------------
// Kernel B: blocks 0..324: pair (i,j): out[b] += f_i(b)^T W_ij f_j(b)
//           block 325: first-order + constants
// block = 512 : lane b = t&127, quarter = t>>7 (p-range / u-range split)
// W reads are wave-uniform -> scalar loads; feat reads coalesced over b.
// ---------------------------------------------------------------------------
__global__ __launch_bounds__(512) void reg_kernel(
    const float* __restrict__ featT,
    const float* __restrict__ rw, const float* __restrict__ rb,
    float* __restrict__ out)
{
    __shared__ float red[B_];
    const int t = threadIdx.x;
    const int b = t & 127;
    const int quarter = t >> 7;
    const int bid = blockIdx.x;

    if (t < B_) red[t] = 0.f;
    __syncthreads();

    float acc = 0.f;

    if (bid == NPOS*(NPOS+1)/2) {           // 325: first order + const
        const int u0 = quarter * (FEAT/4);
        for (int u = u0; u < u0 + FEAT/4; ++u)
            acc += featT[u*B_ + b] * rw[1 + u];
        if (quarter == 0) acc += rw[0] + rb[0];
    } else {
        // decode (i,j) from bid
        int i = 0, r = bid;
        while (r >= NPOS - i) { r -= NPOS - i; ++i; }
        const int j = i + 1 + r;

        float fj[64];
        #pragma unroll
        for (int q = 0; q < 64; ++q)
            fj[q] = featT[(j*64 + q)*B_ + b];

        const int p0 = quarter * 16;
        float fi[16];
        #pragma unroll
        for (int p = 0; p < 16; ++p)
            fi[p] = featT[(i*64 + p0 + p)*B_ + b];

        const int stride = (NPOS - i) * 64;
        const int base   = 1 + FEAT + 4096*(NPOS*i - (i*(i-1))/2)
                         + (j - i - 1)*64;

        for (int p = 0; p < 16; ++p) {
            const int off = __builtin_amdgcn_readfirstlane(base + (p0 + p)*stride);
            const float* wp = rw + off;
            float t0 = 0.f, t1 = 0.f, t2 = 0.f, t3 = 0.f;
            #pragma unroll
            for (int q = 0; q < 64; q += 4) {
                t0 += wp[q+0]*fj[q+0];
                t1 += wp[q+1]*fj[q+1];
                t2 += wp[q+2]*fj[q+2];
                t3 += wp[q+3]*fj[q+3];
            }
            acc += fi[p] * ((t0+t1)+(t2+t3));
        }
    }

    atomicAdd(&red[b], acc);
    __syncthreads();
    if (t < B_) atomicAdd(&out[t], red[t]);
}

// ---------------------------------------------------------------------------
extern "C" void kernel_launch(void* const* d_in, const int* in_sizes, int n_in,
                              void* d_out, int out_size, void* d_ws, size_t ws_size,
                              hipStream_t stream)
{
    const int*   x  = (const int*)  d_in[0];
    const float* w1 = (const float*)d_in[1];
    const float* b1 = (const float*)d_in[2];
    const float* w2 = (const float*)d_in[3];
    const float* b2 = (const float*)d_in[4];
    const float* rw = (const float*)d_in[5];
    const float* rb = (const float*)d_in[6];
    float* out   = (float*)d_out;
    float* featT = (float*)d_ws;            // 1664*128*4 = 852 KB

    hipMemsetAsync(out, 0, B_*sizeof(float), stream);
    conv_kernel<<<dim3(512), dim3(256), 0, stream>>>(x, w1, b1, w2, b2, featT);
    reg_kernel <<<dim3(326), dim3(512), 0, stream>>>(featT, rw, rb, out);
}

// Round 4
// 125.398 us; speedup vs baseline: 1.0037x; 1.0037x over previous
//
#include <hip/hip_runtime.h>

#define B_   128
#define L_   26
#define C1_  128
#define C2_  64
#define K1_  7
#define K2_  5
#define NPOS 25
#define FEAT (L_*C2_)   // 1664
#define NPAIR (NPOS*(NPOS+1)/2)  // 325

// ---------------------------------------------------------------------------
// Kernel A: one-hot -> conv1(k7,relu) -> conv2(k5,relu) -> featT[u][b]
// grid = 128 b * 4 c2-tiles(16 c2 each); block = 256 (4 waves)
// w2 tile (40KB) staged in LDS once per block, consumed via broadcast reads.
// LDS: 15.4K h1 + 40K w2 + xs = ~55.5KB -> 2 blocks/CU.
// ---------------------------------------------------------------------------
__global__ __launch_bounds__(256) void conv_kernel(
    const int*   __restrict__ x,
    const float* __restrict__ w1, const float* __restrict__ b1,
    const float* __restrict__ w2, const float* __restrict__ b2,
    float* __restrict__ featT)
{
    __shared__ float h1s[C1_][L_ + 4];      // [c1][pos+2], pads zero
    __shared__ float w2s[16*C1_*K2_];       // 10240 floats = 40KB
    __shared__ int   xs[L_];

    const int bid = blockIdx.x;
    const int b   = bid >> 2;
    const int c2t = bid & 3;
    const int t   = threadIdx.x;

    if (t < L_)  xs[t] = x[b*L_ + t];
    if (t < C1_) { h1s[t][0] = 0.f; h1s[t][1] = 0.f;
                   h1s[t][L_+2] = 0.f; h1s[t][L_+3] = 0.f; }

    // stage w2 slice for this block's 16 c2: contiguous 10240 floats
    {
        const float* src = w2 + c2t*16*C1_*K2_;
        #pragma unroll
        for (int i = 0; i < 10; ++i) {           // 10*4 = 40 floats/thread
            const int idx = t*4 + i*1024;        // coalesced float4
            *(float4*)&w2s[idx] = *(const float4*)&src[idx];
        }
    }
    __syncthreads();

    // stage 1: h1[c1][l] = relu(b1 + sum_k w1[c1][x[l+k-3]][k])
    for (int idx = t; idx < C1_*L_; idx += 256) {
        const int c1 = idx / L_;
        const int l  = idx - c1*L_;
        float s = b1[c1];
        const float* w1r = w1 + c1*4*K1_;
        #pragma unroll
        for (int k = 0; k < K1_; ++k) {
            const int pos = l + k - 3;
            if (pos >= 0 && pos < L_) s += w1r[xs[pos]*K1_ + k];
        }
        h1s[c1][l+2] = fmaxf(s, 0.f);
    }
    __syncthreads();

    // stage 2: 16 c2 x 26 l outputs from LDS only
    for (int o = t; o < 16*L_; o += 256) {
        const int l   = o % L_;
        const int c2i = o / L_;
        const int c2  = c2t*16 + c2i;
        float acc0 = b2[c2], acc1 = 0.f;
        const float* wbase = &w2s[c2i*C1_*K2_];
        for (int c1 = 0; c1 < C1_; c1 += 2) {
            const float* wr0 = wbase + c1*K2_;
            const float* hr0 = &h1s[c1][l];
            acc0 += wr0[0]*hr0[0] + wr0[1]*hr0[1] + wr0[2]*hr0[2]
                  + wr0[3]*hr0[3] + wr0[4]*hr0[4];
            const float* wr1 = wr0 + K2_;
            const float* hr1 = &h1s[c1+1][l];
            acc1 += wr1[0]*hr1[0] + wr1[1]*hr1[1] + wr1[2]*hr1[2]
                  + wr1[3]*hr1[3] + wr1[4]*hr1[4];
        }
        featT[(l*C2_ + c2)*B_ + b] = fmaxf(acc0 + acc1, 0.f);
    }
}

// ---------------------------------------------------------------------------
// Kernel B: blocks 0..324: pair (i,j): out[b] += f_i(b)^T W_ij f_j(b)
//           block 325: first-order + constants
// W_ij (16KB) staged in LDS via coalesced loads; consumed as float4
// broadcast reads (all b-lanes same address -> conflict-free).
// block = 512: lane b = t&127, quarter = t>>7 owns 16 p-rows.
// ---------------------------------------------------------------------------
__global__ __launch_bounds__(512) void reg_kernel(
    const float* __restrict__ featT,
    const float* __restrict__ rw, const float* __restrict__ rb,
    float* __restrict__ out)
{
    __shared__ float ws[64*64];   // 16KB
    __shared__ float red[B_];
    const int t = threadIdx.x;
    const int b = t & 127;
    const int quarter = t >> 7;
    const int bid = blockIdx.x;

    if (t < B_) red[t] = 0.f;

    float acc = 0.f;

    if (bid == NPAIR) {                      // first order + const
        __syncthreads();
        const int u0 = quarter * (FEAT/4);
        for (int u = u0; u < u0 + FEAT/4; ++u)
            acc += featT[u*B_ + b] * rw[1 + u];
        if (quarter == 0) acc += rw[0] + rb[0];
    } else {
        // decode (i,j) from bid
        int i = 0, r = bid;
        while (r >= NPOS - i) { r -= NPOS - i; ++i; }
        const int j = i + 1 + r;

        const int stride = (NPOS - i) * 64;
        const int base   = 1 + FEAT + 4096*(NPOS*i - (i*(i-1))/2)
                         + (j - i - 1)*64;

        // stage W_ij: row p = rw[base + p*stride .. +64) -> ws[p*64..]
        #pragma unroll
        for (int k = 0; k < 8; ++k) {
            const int idx = t + k*512;       // q consecutive across lanes
            ws[idx] = rw[base + (idx >> 6)*stride + (idx & 63)];
        }
        __syncthreads();

        float fj[64];
        #pragma unroll
        for (int q = 0; q < 64; ++q)
            fj[q] = featT[(j*64 + q)*B_ + b];

        const int p0 = quarter * 16;
        float fi[16];
        #pragma unroll
        for (int p = 0; p < 16; ++p)
            fi[p] = featT[(i*64 + p0 + p)*B_ + b];

        #pragma unroll 4
        for (int p = 0; p < 16; ++p) {
            const float4* wrow = (const float4*)&ws[(p0 + p)*64];
            float s0 = 0.f, s1 = 0.f, s2 = 0.f, s3 = 0.f;
            #pragma unroll
            for (int qq = 0; qq < 16; ++qq) {
                const float4 w = wrow[qq];
                s0 += w.x*fj[qq*4+0];
                s1 += w.y*fj[qq*4+1];
                s2 += w.z*fj[qq*4+2];
                s3 += w.w*fj[qq*4+3];
            }
            acc += fi[p] * ((s0+s1)+(s2+s3));
        }
    }

    atomicAdd(&red[b], acc);
    __syncthreads();
    if (t < B_) atomicAdd(&out[t], red[t]);
}

// ---------------------------------------------------------------------------
extern "C" void kernel_launch(void* const* d_in, const int* in_sizes, int n_in,
                              void* d_out, int out_size, void* d_ws, size_t ws_size,
                              hipStream_t stream)
{
    const int*   x  = (const int*)  d_in[0];
    const float* w1 = (const float*)d_in[1];
    const float* b1 = (const float*)d_in[2];
    const float* w2 = (const float*)d_in[3];
    const float* b2 = (const float*)d_in[4];
    const float* rw = (const float*)d_in[5];
    const float* rb = (const float*)d_in[6];
    float* out   = (float*)d_out;
    float* featT = (float*)d_ws;            // 1664*128*4 = 852 KB

    hipMemsetAsync(out, 0, B_*sizeof(float), stream);
    conv_kernel<<<dim3(512), dim3(256), 0, stream>>>(x, w1, b1, w2, b2, featT);
    reg_kernel <<<dim3(NPAIR+1), dim3(512), 0, stream>>>(featT, rw, rb, out);
}